// Round 1
// baseline (872.117 us; speedup 1.0000x reference)
//
#include <hip/hip_runtime.h>
#include <hip/hip_bf16.h>

// ---------------- CSR build ----------------

__global__ void count_kernel(const int* __restrict__ dst, int* __restrict__ cnt, int E) {
    int stride = gridDim.x * blockDim.x;
    for (int e = blockIdx.x * blockDim.x + threadIdx.x; e < E; e += stride)
        atomicAdd(&cnt[dst[e]], 1);
}

__global__ __launch_bounds__(1024) void scan_part(const int* __restrict__ cnt,
                                                  int* __restrict__ bsum, int Nn) {
    int i = blockIdx.x * 1024 + threadIdx.x;
    int v = (i < Nn) ? cnt[i] : 0;
#pragma unroll
    for (int d = 1; d < 64; d <<= 1) v += __shfl_xor(v, d, 64);
    __shared__ int wsums[16];
    if ((threadIdx.x & 63) == 0) wsums[threadIdx.x >> 6] = v;
    __syncthreads();
    if (threadIdx.x == 0) {
        int s = 0;
        for (int w = 0; w < 16; ++w) s += wsums[w];
        bsum[blockIdx.x] = s;
    }
}

__global__ void scan_top(int* __restrict__ bsum, int NB) {
    if (blockIdx.x == 0 && threadIdx.x == 0) {
        int run = 0;
        for (int b = 0; b < NB; ++b) { int t = bsum[b]; bsum[b] = run; run += t; }
    }
}

__global__ __launch_bounds__(1024) void scan_final(const int* __restrict__ cnt,
                                                   const int* __restrict__ bpre,
                                                   int* __restrict__ offs, int* __restrict__ cursor,
                                                   float* __restrict__ dis, int Nn, int E) {
    int i = blockIdx.x * 1024 + threadIdx.x;
    int v = (i < Nn) ? cnt[i] : 0;
    int lane = threadIdx.x & 63, wid = threadIdx.x >> 6;
    int x = v;
#pragma unroll
    for (int d = 1; d < 64; d <<= 1) {
        int y = __shfl_up(x, d, 64);
        if (lane >= d) x += y;
    }
    __shared__ int wsum[16];
    __shared__ int wpre[16];
    if (lane == 63) wsum[wid] = x;
    __syncthreads();
    if (threadIdx.x == 0) {
        int run = 0;
        for (int w = 0; w < 16; ++w) { wpre[w] = run; run += wsum[w]; }
    }
    __syncthreads();
    int excl = x - v + wpre[wid] + bpre[blockIdx.x];
    if (i < Nn) {
        offs[i] = excl;
        cursor[i] = excl;
        dis[i] = rsqrtf((float)v + 1.0f);
    }
    if (blockIdx.x == 0 && threadIdx.x == 0) offs[Nn] = E;
}

__global__ void fill_kernel(const int* __restrict__ src, const int* __restrict__ dst,
                            int* __restrict__ cursor, int* __restrict__ ssrc, int E) {
    int stride = gridDim.x * blockDim.x;
    for (int e = blockIdx.x * blockDim.x + threadIdx.x; e < E; e += stride) {
        int d = dst[e];
        int p = atomicAdd(&cursor[d], 1);
        ssrc[p] = src[e];
    }
}

// ---------------- dense GEMM: C[M,N] = A[M,K] @ W[K,N] ----------------
// block: 256 threads, 64 rows per block. Thread (tcol=tid&63, trow=tid>>6)
// computes rows trow*16..trow*16+15 x cols {tcol + 64*c}.

template <int K, int N>
__global__ __launch_bounds__(256) void gemm_kernel(const float* __restrict__ A,
                                                   const float* __restrict__ W,
                                                   float* __restrict__ C, int M) {
    __shared__ __align__(16) float As[64 * K];
    int m0 = blockIdx.x * 64;
    int tid = threadIdx.x;
    int rlim = M - m0;
    if (rlim > 64) rlim = 64;
    const float4* A4 = reinterpret_cast<const float4*>(A + (size_t)m0 * K);
    int validv = rlim * (K / 4);
    constexpr int NV = 64 * K / 4;
    for (int i = tid; i < NV; i += 256) {
        float4 vv = (i < validv) ? A4[i] : make_float4(0.f, 0.f, 0.f, 0.f);
        reinterpret_cast<float4*>(As)[i] = vv;
    }
    __syncthreads();
    constexpr int CPT = N / 64;
    int tcol = tid & 63;
    int trow = tid >> 6;
    float acc[16][CPT];
#pragma unroll
    for (int i = 0; i < 16; ++i)
#pragma unroll
        for (int c = 0; c < CPT; ++c) acc[i][c] = 0.f;

#pragma unroll 2
    for (int k = 0; k < K; k += 4) {
        float w[4][CPT];
#pragma unroll
        for (int j = 0; j < 4; ++j)
#pragma unroll
            for (int c = 0; c < CPT; ++c) w[j][c] = W[(k + j) * N + tcol + 64 * c];
#pragma unroll
        for (int i = 0; i < 16; ++i) {
            float4 a = *reinterpret_cast<const float4*>(&As[(trow * 16 + i) * K + k]);
#pragma unroll
            for (int c = 0; c < CPT; ++c)
                acc[i][c] += a.x * w[0][c] + a.y * w[1][c] + a.z * w[2][c] + a.w * w[3][c];
        }
    }
#pragma unroll
    for (int i = 0; i < 16; ++i) {
        int r = trow * 16 + i;
        if (r < rlim) {
#pragma unroll
            for (int c = 0; c < CPT; ++c)
                C[(size_t)(m0 + r) * N + tcol + 64 * c] = acc[i][c];
        }
    }
}

// ---------------- aggregation layer 1 (256 cols) + bias + L2 normalize ----------------
// one wave per node; each lane owns 4 columns (float4)

__global__ __launch_bounds__(256) void agg1_kernel(const float* __restrict__ h,
                                                   const int* __restrict__ offs,
                                                   const int* __restrict__ ssrc,
                                                   const float* __restrict__ dis,
                                                   const float* __restrict__ b,
                                                   float* __restrict__ xout, int Nn) {
    int gw = (int)((blockIdx.x * blockDim.x + threadIdx.x) >> 6);
    int lane = threadIdx.x & 63;
    if (gw >= Nn) return;
    float dn = dis[gw];
    int e0 = offs[gw], e1 = offs[gw + 1];
    float4 hv = reinterpret_cast<const float4*>(h + (size_t)gw * 256)[lane];
    float sw = dn * dn;
    float ax = hv.x * sw, ay = hv.y * sw, az = hv.z * sw, aw = hv.w * sw;
    for (int e = e0; e < e1; ++e) {
        int s = ssrc[e];
        float f = dis[s] * dn;
        float4 v = reinterpret_cast<const float4*>(h + (size_t)s * 256)[lane];
        ax += v.x * f;
        ay += v.y * f;
        az += v.z * f;
        aw += v.w * f;
    }
    float4 bv = reinterpret_cast<const float4*>(b)[lane];
    ax += bv.x; ay += bv.y; az += bv.z; aw += bv.w;
    float ss = ax * ax + ay * ay + az * az + aw * aw;
#pragma unroll
    for (int d = 1; d < 64; d <<= 1) ss += __shfl_xor(ss, d, 64);
    float inv = 1.0f / fmaxf(sqrtf(ss), 1e-12f);
    float4 o;
    o.x = ax * inv; o.y = ay * inv; o.z = az * inv; o.w = aw * inv;
    reinterpret_cast<float4*>(xout + (size_t)gw * 256)[lane] = o;
}

// ---------------- aggregation layer 2 (128 cols) + bias ----------------

__global__ __launch_bounds__(256) void agg2_kernel(const float* __restrict__ h,
                                                   const int* __restrict__ offs,
                                                   const int* __restrict__ ssrc,
                                                   const float* __restrict__ dis,
                                                   const float* __restrict__ b,
                                                   float* __restrict__ out, int Nn) {
    int gw = (int)((blockIdx.x * blockDim.x + threadIdx.x) >> 6);
    int lane = threadIdx.x & 63;
    if (gw >= Nn) return;
    float dn = dis[gw];
    int e0 = offs[gw], e1 = offs[gw + 1];
    float2 hv = reinterpret_cast<const float2*>(h + (size_t)gw * 128)[lane];
    float sw = dn * dn;
    float ax = hv.x * sw, ay = hv.y * sw;
    for (int e = e0; e < e1; ++e) {
        int s = ssrc[e];
        float f = dis[s] * dn;
        float2 v = reinterpret_cast<const float2*>(h + (size_t)s * 128)[lane];
        ax += v.x * f;
        ay += v.y * f;
    }
    float2 bv = reinterpret_cast<const float2*>(b)[lane];
    ax += bv.x; ay += bv.y;
    float2 o;
    o.x = ax; o.y = ay;
    reinterpret_cast<float2*>(out + (size_t)gw * 128)[lane] = o;
}

// ---------------- launch ----------------

extern "C" void kernel_launch(void* const* d_in, const int* in_sizes, int n_in,
                              void* d_out, int out_size, void* d_ws, size_t ws_size,
                              hipStream_t stream) {
    const float* emb = (const float*)d_in[0];
    const float* W1 = (const float*)d_in[1];
    const float* b1 = (const float*)d_in[2];
    const float* W2 = (const float*)d_in[3];
    const float* b2 = (const float*)d_in[4];
    const int* eidx = (const int*)d_in[5];

    const int Nn = in_sizes[0] / 128;   // 100000
    const int E = in_sizes[5] / 2;      // 1600000
    const int* srcp = eidx;
    const int* dstp = eidx + E;

    float* ws = (float*)d_ws;
    size_t o = 0;
    float* h1 = ws + o;     o += (size_t)Nn * 256;   // also reused as h2 later
    float* xb = ws + o;     o += (size_t)Nn * 256;
    float* dis = ws + o;    o += Nn;
    int* cnt = (int*)(ws + o);    o += Nn;
    int* offs = (int*)(ws + o);   o += Nn + 16;
    int* cursor = (int*)(ws + o); o += Nn;
    int* bsum = (int*)(ws + o);   o += 128;
    int* ssrc = (int*)(ws + o);   o += E;

    hipMemsetAsync(cnt, 0, (size_t)Nn * sizeof(int), stream);

    count_kernel<<<1024, 256, 0, stream>>>(dstp, cnt, E);
    int NB = (Nn + 1023) / 1024;  // 98
    scan_part<<<NB, 1024, 0, stream>>>(cnt, bsum, Nn);
    scan_top<<<1, 64, 0, stream>>>(bsum, NB);
    scan_final<<<NB, 1024, 0, stream>>>(cnt, bsum, offs, cursor, dis, Nn, E);
    fill_kernel<<<1024, 256, 0, stream>>>(srcp, dstp, cursor, ssrc, E);

    gemm_kernel<128, 256><<<(Nn + 63) / 64, 256, 0, stream>>>(emb, W1, h1, Nn);
    agg1_kernel<<<(Nn + 3) / 4, 256, 0, stream>>>(h1, offs, ssrc, dis, b1, xb, Nn);
    float* h2 = h1;
    gemm_kernel<256, 128><<<(Nn + 63) / 64, 256, 0, stream>>>(xb, W2, h2, Nn);
    agg2_kernel<<<(Nn + 3) / 4, 256, 0, stream>>>(h2, offs, ssrc, dis, b2, (float*)d_out, Nn);
}

// Round 2
// 768.874 us; speedup vs baseline: 1.1343x; 1.1343x over previous
//
#include <hip/hip_runtime.h>
#include <hip/hip_bf16.h>

// ---------------- helpers ----------------

__device__ __forceinline__ ushort f2bf(float f) {
    unsigned int b = __float_as_uint(f);
    unsigned int r = (b + 0x7fffu + ((b >> 16) & 1u)) >> 16;  // RNE
    return (ushort)r;
}

// ---------------- CSR build ----------------

__global__ void count_kernel(const int* __restrict__ dst, int* __restrict__ cnt, int E) {
    int stride = gridDim.x * blockDim.x;
    for (int e = blockIdx.x * blockDim.x + threadIdx.x; e < E; e += stride)
        atomicAdd(&cnt[dst[e]], 1);
}

__global__ __launch_bounds__(1024) void scan_part(const int* __restrict__ cnt,
                                                  int* __restrict__ bsum, int Nn) {
    int i = blockIdx.x * 1024 + threadIdx.x;
    int v = (i < Nn) ? cnt[i] : 0;
#pragma unroll
    for (int d = 1; d < 64; d <<= 1) v += __shfl_xor(v, d, 64);
    __shared__ int wsums[16];
    if ((threadIdx.x & 63) == 0) wsums[threadIdx.x >> 6] = v;
    __syncthreads();
    if (threadIdx.x == 0) {
        int s = 0;
        for (int w = 0; w < 16; ++w) s += wsums[w];
        bsum[blockIdx.x] = s;
    }
}

__global__ void scan_top(int* __restrict__ bsum, int NB) {
    if (blockIdx.x == 0 && threadIdx.x == 0) {
        int run = 0;
        for (int b = 0; b < NB; ++b) { int t = bsum[b]; bsum[b] = run; run += t; }
    }
}

__global__ __launch_bounds__(1024) void scan_final(const int* __restrict__ cnt,
                                                   const int* __restrict__ bpre,
                                                   int* __restrict__ offs, int* __restrict__ cursor,
                                                   float* __restrict__ dis, int Nn, int E) {
    int i = blockIdx.x * 1024 + threadIdx.x;
    int v = (i < Nn) ? cnt[i] : 0;
    int lane = threadIdx.x & 63, wid = threadIdx.x >> 6;
    int x = v;
#pragma unroll
    for (int d = 1; d < 64; d <<= 1) {
        int y = __shfl_up(x, d, 64);
        if (lane >= d) x += y;
    }
    __shared__ int wsum[16];
    __shared__ int wpre[16];
    if (lane == 63) wsum[wid] = x;
    __syncthreads();
    if (threadIdx.x == 0) {
        int run = 0;
        for (int w = 0; w < 16; ++w) { wpre[w] = run; run += wsum[w]; }
    }
    __syncthreads();
    int excl = x - v + wpre[wid] + bpre[blockIdx.x];
    if (i < Nn) {
        offs[i] = excl;
        cursor[i] = excl;
        dis[i] = rsqrtf((float)v + 1.0f);
    }
    if (blockIdx.x == 0 && threadIdx.x == 0) offs[Nn] = E;
}

__global__ void fill_kernel(const int* __restrict__ src, const int* __restrict__ dst,
                            int* __restrict__ cursor, int* __restrict__ ssrc, int E) {
    int stride = gridDim.x * blockDim.x;
    for (int e = blockIdx.x * blockDim.x + threadIdx.x; e < E; e += stride) {
        int d = dst[e];
        int p = atomicAdd(&cursor[d], 1);
        ssrc[p] = src[e];
    }
}

// ---------------- fp32 -> bf16 cast (packed table for gathers) ----------------

__global__ void cast_bf16_kernel(const float4* __restrict__ in, ushort4* __restrict__ out, int n4) {
    int stride = gridDim.x * blockDim.x;
    for (int i = blockIdx.x * blockDim.x + threadIdx.x; i < n4; i += stride) {
        float4 v = in[i];
        ushort4 o;
        o.x = f2bf(v.x); o.y = f2bf(v.y); o.z = f2bf(v.z); o.w = f2bf(v.w);
        out[i] = o;
    }
}

// ---------------- aggregation over 128 bf16 cols ----------------
// one wave per node; lane owns cols {2*lane, 2*lane+1} packed in one uint.
// out (fp32) = sum_{e in N(dst)} dis[src]*dis[dst]*tbl[src] + dis[dst]^2*tbl[dst]  (+bias)

template <bool BIAS>
__global__ __launch_bounds__(256) void agg128_kernel(const uint* __restrict__ tbl,  // [Nn*64]
                                                     const int* __restrict__ offs,
                                                     const int* __restrict__ ssrc,
                                                     const float* __restrict__ dis,
                                                     const float* __restrict__ bias,
                                                     float* __restrict__ out,  // [Nn*128]
                                                     int Nn) {
    int gw = (int)((blockIdx.x * blockDim.x + threadIdx.x) >> 6);
    int lane = threadIdx.x & 63;
    if (gw >= Nn) return;
    float dn = dis[gw];
    int e0 = offs[gw], e1 = offs[gw + 1];
    uint hv = tbl[(size_t)gw * 64 + lane];
    float sw = dn * dn;
    float ax = __uint_as_float(hv << 16) * sw;
    float ay = __uint_as_float(hv & 0xffff0000u) * sw;
    for (int e = e0; e < e1; ++e) {
        int s = ssrc[e];
        float f = dis[s] * dn;
        uint v = tbl[(size_t)s * 64 + lane];
        ax += __uint_as_float(v << 16) * f;
        ay += __uint_as_float(v & 0xffff0000u) * f;
    }
    if (BIAS) {
        float2 bv = reinterpret_cast<const float2*>(bias)[lane];
        ax += bv.x; ay += bv.y;
    }
    float2 o;
    o.x = ax; o.y = ay;
    reinterpret_cast<float2*>(out)[(size_t)gw * 64 + lane] = o;
}

// ---------------- dense GEMM: C[M,N] = A[M,K] @ W[K,N] (+bias, +row-L2-norm, bf16 out opt) ----------------
// block: 256 threads, 64 rows per block. Thread (tcol=tid&63, trow=tid>>6)
// computes rows trow*16..trow*16+15 x cols {tcol + 64*c}. A wave owns complete rows.

template <int K, int N, bool BIAS, bool NORM, bool BF16OUT>
__global__ __launch_bounds__(256) void gemm_kernel(const float* __restrict__ A,
                                                   const float* __restrict__ W,
                                                   const float* __restrict__ bias,
                                                   float* __restrict__ C,
                                                   ushort* __restrict__ Cb, int M) {
    __shared__ __align__(16) float As[64 * K];
    int m0 = blockIdx.x * 64;
    int tid = threadIdx.x;
    int rlim = M - m0;
    if (rlim > 64) rlim = 64;
    const float4* A4 = reinterpret_cast<const float4*>(A + (size_t)m0 * K);
    int validv = rlim * (K / 4);
    constexpr int NV = 64 * K / 4;
    for (int i = tid; i < NV; i += 256) {
        float4 vv = (i < validv) ? A4[i] : make_float4(0.f, 0.f, 0.f, 0.f);
        reinterpret_cast<float4*>(As)[i] = vv;
    }
    __syncthreads();
    constexpr int CPT = N / 64;
    int tcol = tid & 63;
    int trow = tid >> 6;
    float acc[16][CPT];
#pragma unroll
    for (int i = 0; i < 16; ++i)
#pragma unroll
        for (int c = 0; c < CPT; ++c) acc[i][c] = 0.f;

#pragma unroll 2
    for (int k = 0; k < K; k += 4) {
        float w[4][CPT];
#pragma unroll
        for (int j = 0; j < 4; ++j)
#pragma unroll
            for (int c = 0; c < CPT; ++c) w[j][c] = W[(k + j) * N + tcol + 64 * c];
#pragma unroll
        for (int i = 0; i < 16; ++i) {
            float4 a = *reinterpret_cast<const float4*>(&As[(trow * 16 + i) * K + k]);
#pragma unroll
            for (int c = 0; c < CPT; ++c)
                acc[i][c] += a.x * w[0][c] + a.y * w[1][c] + a.z * w[2][c] + a.w * w[3][c];
        }
    }

    float bv[CPT];
    if (BIAS) {
#pragma unroll
        for (int c = 0; c < CPT; ++c) bv[c] = bias[tcol + 64 * c];
    }

#pragma unroll
    for (int i = 0; i < 16; ++i) {
        int r = trow * 16 + i;
        if (BIAS) {
#pragma unroll
            for (int c = 0; c < CPT; ++c) acc[i][c] += bv[c];
        }
        float inv = 1.0f;
        if (NORM) {
            float ss = 0.f;
#pragma unroll
            for (int c = 0; c < CPT; ++c) ss += acc[i][c] * acc[i][c];
#pragma unroll
            for (int d = 1; d < 64; d <<= 1) ss += __shfl_xor(ss, d, 64);
            inv = 1.0f / fmaxf(sqrtf(ss), 1e-12f);
        }
        if (r < rlim) {
#pragma unroll
            for (int c = 0; c < CPT; ++c) {
                float v = acc[i][c] * inv;
                if (BF16OUT)
                    Cb[(size_t)(m0 + r) * N + tcol + 64 * c] = f2bf(v);
                else
                    C[(size_t)(m0 + r) * N + tcol + 64 * c] = v;
            }
        }
    }
}

// ---------------- launch ----------------

extern "C" void kernel_launch(void* const* d_in, const int* in_sizes, int n_in,
                              void* d_out, int out_size, void* d_ws, size_t ws_size,
                              hipStream_t stream) {
    const float* emb = (const float*)d_in[0];
    const float* W1 = (const float*)d_in[1];
    const float* b1 = (const float*)d_in[2];
    const float* W2 = (const float*)d_in[3];
    const float* b2 = (const float*)d_in[4];
    const int* eidx = (const int*)d_in[5];

    const int Nn = in_sizes[0] / 128;   // 100000
    const int E = in_sizes[5] / 2;      // 1600000
    const int* srcp = eidx;
    const int* dstp = eidx + E;

    float* ws = (float*)d_ws;
    size_t o = 0;
    float* ax = ws + o;     o += (size_t)Nn * 128;   // aggregated emb (fp32)
    float* xb = ws + o;     o += (size_t)Nn * 256;   // normalized layer-1 output (fp32)
    uint* embb = (uint*)(ws + o);  o += (size_t)Nn * 64;  // emb as bf16 pairs
    uint* h2b = (uint*)(ws + o);   o += (size_t)Nn * 64;  // h2 as bf16 pairs
    float* dis = ws + o;    o += Nn;
    int* cnt = (int*)(ws + o);    o += Nn;
    int* offs = (int*)(ws + o);   o += Nn + 16;
    int* cursor = (int*)(ws + o); o += Nn;
    int* bsum = (int*)(ws + o);   o += 128;
    int* ssrc = (int*)(ws + o);   o += E;

    hipMemsetAsync(cnt, 0, (size_t)Nn * sizeof(int), stream);

    count_kernel<<<1024, 256, 0, stream>>>(dstp, cnt, E);
    int NB = (Nn + 1023) / 1024;  // 98
    scan_part<<<NB, 1024, 0, stream>>>(cnt, bsum, Nn);
    scan_top<<<1, 64, 0, stream>>>(bsum, NB);
    scan_final<<<NB, 1024, 0, stream>>>(cnt, bsum, offs, cursor, dis, Nn, E);
    fill_kernel<<<1024, 256, 0, stream>>>(srcp, dstp, cursor, ssrc, E);

    // emb -> bf16 table
    cast_bf16_kernel<<<2048, 256, 0, stream>>>((const float4*)emb, (ushort4*)embb, Nn * 128 / 4);

    // layer 1: aggregate emb (128 cols), then GEMM 128->256 with bias + L2 normalize
    agg128_kernel<false><<<(Nn + 3) / 4, 256, 0, stream>>>(embb, offs, ssrc, dis, nullptr, ax, Nn);
    gemm_kernel<128, 256, true, true, false><<<(Nn + 63) / 64, 256, 0, stream>>>(ax, W1, b1, xb, nullptr, Nn);

    // layer 2: GEMM 256->128 (bf16 out, no bias), aggregate (128 cols) + bias
    gemm_kernel<256, 128, false, false, true><<<(Nn + 63) / 64, 256, 0, stream>>>(xb, W2, nullptr, nullptr, (ushort*)h2b, Nn);
    agg128_kernel<true><<<(Nn + 3) / 4, 256, 0, stream>>>(h2b, offs, ssrc, dis, b2, (float*)d_out, Nn);
}

// Round 3
// 427.071 us; speedup vs baseline: 2.0421x; 1.8003x over previous
//
#include <hip/hip_runtime.h>
#include <hip/hip_bf16.h>

typedef __attribute__((ext_vector_type(8))) short bf16x8;
typedef __attribute__((ext_vector_type(4))) float f32x4;

// ---------------- helpers ----------------

__device__ __forceinline__ ushort f2bf(float f) {
    unsigned int b = __float_as_uint(f);
    unsigned int r = (b + 0x7fffu + ((b >> 16) & 1u)) >> 16;  // RNE
    return (ushort)r;
}
__device__ __forceinline__ float bflo(uint v) { return __uint_as_float(v << 16); }
__device__ __forceinline__ float bfhi(uint v) { return __uint_as_float(v & 0xffff0000u); }

// ---------------- CSR build ----------------

__global__ void count_kernel(const int* __restrict__ dst, int* __restrict__ cnt, int E) {
    int stride = gridDim.x * blockDim.x;
    for (int e = blockIdx.x * blockDim.x + threadIdx.x; e < E; e += stride)
        atomicAdd(&cnt[dst[e]], 1);
}

__global__ __launch_bounds__(1024) void scan_part(const int* __restrict__ cnt,
                                                  int* __restrict__ bsum, int Nn) {
    int i = blockIdx.x * 1024 + threadIdx.x;
    int v = (i < Nn) ? cnt[i] : 0;
#pragma unroll
    for (int d = 1; d < 64; d <<= 1) v += __shfl_xor(v, d, 64);
    __shared__ int wsums[16];
    if ((threadIdx.x & 63) == 0) wsums[threadIdx.x >> 6] = v;
    __syncthreads();
    if (threadIdx.x == 0) {
        int s = 0;
        for (int w = 0; w < 16; ++w) s += wsums[w];
        bsum[blockIdx.x] = s;
    }
}

// parallel exclusive scan over NB<=128 block sums (1 block, 128 threads)
__global__ __launch_bounds__(128) void scan_top(int* __restrict__ bsum, int NB) {
    int i = threadIdx.x;
    int v = (i < NB) ? bsum[i] : 0;
    int x = v;
#pragma unroll
    for (int d = 1; d < 64; d <<= 1) {
        int y = __shfl_up(x, d, 64);
        if ((i & 63) >= d) x += y;
    }
    __shared__ int w0;
    if (i == 63) w0 = x;
    __syncthreads();
    if (i >= 64) x += w0;
    if (i < NB) bsum[i] = x - v;
}

__global__ __launch_bounds__(1024) void scan_final(const int* __restrict__ cnt,
                                                   const int* __restrict__ bpre,
                                                   int* __restrict__ offs, int* __restrict__ cursor,
                                                   float* __restrict__ dis, int Nn, int E) {
    int i = blockIdx.x * 1024 + threadIdx.x;
    int v = (i < Nn) ? cnt[i] : 0;
    int lane = threadIdx.x & 63, wid = threadIdx.x >> 6;
    int x = v;
#pragma unroll
    for (int d = 1; d < 64; d <<= 1) {
        int y = __shfl_up(x, d, 64);
        if (lane >= d) x += y;
    }
    __shared__ int wsum[16];
    __shared__ int wpre[16];
    if (lane == 63) wsum[wid] = x;
    __syncthreads();
    if (threadIdx.x == 0) {
        int run = 0;
        for (int w = 0; w < 16; ++w) { wpre[w] = run; run += wsum[w]; }
    }
    __syncthreads();
    int excl = x - v + wpre[wid] + bpre[blockIdx.x];
    if (i < Nn) {
        offs[i] = excl;
        cursor[i] = excl;
        dis[i] = rsqrtf((float)v + 1.0f);
    }
    if (blockIdx.x == 0 && threadIdx.x == 0) offs[Nn] = E;
}

// fill packed edge records {src, dis[src]}
__global__ void fill_kernel(const int* __restrict__ src, const int* __restrict__ dst,
                            const float* __restrict__ dis,
                            int* __restrict__ cursor, int2* __restrict__ rec, int E) {
    int stride = gridDim.x * blockDim.x;
    for (int e = blockIdx.x * blockDim.x + threadIdx.x; e < E; e += stride) {
        int d = dst[e];
        int s = src[e];
        int p = atomicAdd(&cursor[d], 1);
        int2 r;
        r.x = s;
        r.y = __float_as_int(dis[s]);
        rec[p] = r;
    }
}

// ---------------- casts ----------------

__global__ void cast_bf16_kernel(const float4* __restrict__ in, ushort4* __restrict__ out, int n4) {
    int stride = gridDim.x * blockDim.x;
    for (int i = blockIdx.x * blockDim.x + threadIdx.x; i < n4; i += stride) {
        float4 v = in[i];
        ushort4 o;
        o.x = f2bf(v.x); o.y = f2bf(v.y); o.z = f2bf(v.z); o.w = f2bf(v.w);
        out[i] = o;
    }
}

// Wt[n][k] = bf16(W[k][n]); total = Kd*Nd elements, Wt is [Nd][Kd]
__global__ void castT_kernel(const float* __restrict__ W, ushort* __restrict__ Wt, int Kd, int Nd) {
    int i = blockIdx.x * 256 + threadIdx.x;
    if (i >= Kd * Nd) return;
    int n = i / Kd, k = i % Kd;
    Wt[i] = f2bf(W[(size_t)k * Nd + n]);
}

// ---------------- aggregation over 128 bf16 cols ----------------
// one wave per node; lane owns cols {2*lane, 2*lane+1} packed in one uint.
// 4-wide edge batching for memory-level parallelism.

template <bool BIAS, bool BF16OUT>
__global__ __launch_bounds__(256) void agg_kernel(const uint* __restrict__ tbl,   // [Nn][64]
                                                  const int* __restrict__ offs,
                                                  const int2* __restrict__ rec,   // {src, dis[src]}
                                                  const float* __restrict__ dis,
                                                  const float* __restrict__ bias,
                                                  void* __restrict__ outp, int Nn) {
    int gw = (int)((blockIdx.x * 256 + threadIdx.x) >> 6);
    int lane = threadIdx.x & 63;
    if (gw >= Nn) return;
    float dn = dis[gw];
    int e0 = offs[gw], e1 = offs[gw + 1];
    uint hv = tbl[(size_t)gw * 64 + lane];
    float sw = dn * dn;
    float ax = bflo(hv) * sw, ay = bfhi(hv) * sw;
    int e = e0;
    for (; e + 4 <= e1; e += 4) {
        int2 r0 = rec[e], r1 = rec[e + 1], r2 = rec[e + 2], r3 = rec[e + 3];
        uint v0 = tbl[(size_t)r0.x * 64 + lane];
        uint v1 = tbl[(size_t)r1.x * 64 + lane];
        uint v2 = tbl[(size_t)r2.x * 64 + lane];
        uint v3 = tbl[(size_t)r3.x * 64 + lane];
        float f0 = __int_as_float(r0.y) * dn;
        float f1 = __int_as_float(r1.y) * dn;
        float f2 = __int_as_float(r2.y) * dn;
        float f3 = __int_as_float(r3.y) * dn;
        ax += bflo(v0) * f0; ay += bfhi(v0) * f0;
        ax += bflo(v1) * f1; ay += bfhi(v1) * f1;
        ax += bflo(v2) * f2; ay += bfhi(v2) * f2;
        ax += bflo(v3) * f3; ay += bfhi(v3) * f3;
    }
    for (; e < e1; ++e) {
        int2 r = rec[e];
        uint v = tbl[(size_t)r.x * 64 + lane];
        float f = __int_as_float(r.y) * dn;
        ax += bflo(v) * f; ay += bfhi(v) * f;
    }
    if (BIAS) {
        float2 bv = reinterpret_cast<const float2*>(bias)[lane];
        ax += bv.x; ay += bv.y;
    }
    if (BF16OUT) {
        reinterpret_cast<uint*>(outp)[(size_t)gw * 64 + lane] =
            (uint)f2bf(ax) | ((uint)f2bf(ay) << 16);
    } else {
        float2 o; o.x = ax; o.y = ay;
        reinterpret_cast<float2*>(outp)[(size_t)gw * 64 + lane] = o;
    }
}

// ---------------- MFMA GEMM: C[M,N] = A[M,K] @ W[K,N], A bf16 row-major, Wt[n][k] bf16 ----------------
// block = 4 waves, tile 64 rows x N cols; wave w owns cols [w*N/4, (w+1)*N/4).
// mfma_f32_16x16x32_bf16: A-frag row=lane&15, k=(lane>>4)*8+j; B-frag col=lane&15, same k;
// C/D col=lane&15, row=(lane>>4)*4+reg  [measured m89].
// FIN: add bias, L2-normalize rows (cross-wave via LDS), write bf16. else: plain bf16 write.

template <int K, int N, bool FIN>
__global__ __launch_bounds__(256) void mfma_gemm(const ushort* __restrict__ A,
                                                 const ushort* __restrict__ Wt,
                                                 const float* __restrict__ bias,
                                                 ushort* __restrict__ Cb, int M) {
    constexpr int NS = N / 64;   // n-subtiles per wave
    constexpr int KS = K / 32;   // k-steps
    int lane = threadIdx.x & 63, wid = threadIdx.x >> 6;
    int m0 = blockIdx.x * 64;
    int koff = (lane >> 4) * 8;

    const bf16x8* ap[4];
#pragma unroll
    for (int ms = 0; ms < 4; ++ms) {
        int r = m0 + ms * 16 + (lane & 15);
        if (r >= M) r = M - 1;
        ap[ms] = reinterpret_cast<const bf16x8*>(A + (size_t)r * K + koff);
    }
    const bf16x8* bp[NS];
#pragma unroll
    for (int ns = 0; ns < NS; ++ns) {
        int c = wid * (N / 4) + ns * 16 + (lane & 15);
        bp[ns] = reinterpret_cast<const bf16x8*>(Wt + (size_t)c * K + koff);
    }

    f32x4 acc[4][NS];
#pragma unroll
    for (int ms = 0; ms < 4; ++ms)
#pragma unroll
        for (int ns = 0; ns < NS; ++ns) acc[ms][ns] = (f32x4){0.f, 0.f, 0.f, 0.f};

#pragma unroll
    for (int ks = 0; ks < KS; ++ks) {
        bf16x8 a[4], b[NS];
#pragma unroll
        for (int ms = 0; ms < 4; ++ms) a[ms] = ap[ms][ks * 4];
#pragma unroll
        for (int ns = 0; ns < NS; ++ns) b[ns] = bp[ns][ks * 4];
#pragma unroll
        for (int ms = 0; ms < 4; ++ms)
#pragma unroll
            for (int ns = 0; ns < NS; ++ns)
                acc[ms][ns] = __builtin_amdgcn_mfma_f32_16x16x32_bf16(a[ms], b[ns], acc[ms][ns], 0, 0, 0);
    }

    if (FIN) {
        // bias
        float bv[NS];
#pragma unroll
        for (int ns = 0; ns < NS; ++ns) bv[ns] = bias[wid * (N / 4) + ns * 16 + (lane & 15)];
        // per-lane partial row sum-of-squares
        float ps[4][4];
#pragma unroll
        for (int ms = 0; ms < 4; ++ms)
#pragma unroll
            for (int r = 0; r < 4; ++r) {
                float s = 0.f;
#pragma unroll
                for (int ns = 0; ns < NS; ++ns) {
                    float v = acc[ms][ns][r] + bv[ns];
                    acc[ms][ns][r] = v;
                    s += v * v;
                }
                ps[ms][r] = s;
            }
        // reduce over 16 cols within wave
#pragma unroll
        for (int d = 1; d < 16; d <<= 1)
#pragma unroll
            for (int ms = 0; ms < 4; ++ms)
#pragma unroll
                for (int r = 0; r < 4; ++r) ps[ms][r] += __shfl_xor(ps[ms][r], d, 64);
        // cross-wave reduce via LDS
        __shared__ float ssl[4][64];
        if ((lane & 15) == 0) {
#pragma unroll
            for (int ms = 0; ms < 4; ++ms)
#pragma unroll
                for (int r = 0; r < 4; ++r) ssl[wid][ms * 16 + (lane >> 4) * 4 + r] = ps[ms][r];
        }
        __syncthreads();
#pragma unroll
        for (int ms = 0; ms < 4; ++ms)
#pragma unroll
            for (int r = 0; r < 4; ++r) {
                int rt = ms * 16 + (lane >> 4) * 4 + r;
                float tot = ssl[0][rt] + ssl[1][rt] + ssl[2][rt] + ssl[3][rt];
                float inv = 1.0f / fmaxf(sqrtf(tot), 1e-12f);
                int row = m0 + rt;
                if (row < M) {
#pragma unroll
                    for (int ns = 0; ns < NS; ++ns)
                        Cb[(size_t)row * N + wid * (N / 4) + ns * 16 + (lane & 15)] =
                            f2bf(acc[ms][ns][r] * inv);
                }
            }
    } else {
#pragma unroll
        for (int ms = 0; ms < 4; ++ms)
#pragma unroll
            for (int r = 0; r < 4; ++r) {
                int row = m0 + ms * 16 + (lane >> 4) * 4 + r;
                if (row < M) {
#pragma unroll
                    for (int ns = 0; ns < NS; ++ns)
                        Cb[(size_t)row * N + wid * (N / 4) + ns * 16 + (lane & 15)] =
                            f2bf(acc[ms][ns][r]);
                }
            }
    }
}

// ---------------- launch ----------------

extern "C" void kernel_launch(void* const* d_in, const int* in_sizes, int n_in,
                              void* d_out, int out_size, void* d_ws, size_t ws_size,
                              hipStream_t stream) {
    const float* emb = (const float*)d_in[0];
    const float* W1 = (const float*)d_in[1];
    const float* b1 = (const float*)d_in[2];
    const float* W2 = (const float*)d_in[3];
    const float* b2 = (const float*)d_in[4];
    const int* eidx = (const int*)d_in[5];

    const int Nn = in_sizes[0] / 128;   // 100000
    const int E = in_sizes[5] / 2;      // 1600000
    const int* srcp = eidx;
    const int* dstp = eidx + E;

    float* ws = (float*)d_ws;
    size_t o = 0;
    uint* embb = (uint*)(ws + o);  o += (size_t)Nn * 64;   // emb bf16 [Nn][128]
    uint* axb = (uint*)(ws + o);   o += (size_t)Nn * 64;   // agg1 out bf16 [Nn][128]
    uint* xbb = (uint*)(ws + o);   o += (size_t)Nn * 128;  // layer1 out bf16 [Nn][256]
    uint* h2b = (uint*)(ws + o);   o += (size_t)Nn * 64;   // layer2 gemm out bf16 [Nn][128]
    ushort* W1t = (ushort*)(ws + o); o += 128 * 256 / 2;   // [256][128]
    ushort* W2t = (ushort*)(ws + o); o += 256 * 128 / 2;   // [128][256]
    float* dis = ws + o;    o += Nn;
    int* cnt = (int*)(ws + o);    o += Nn;
    int* offs = (int*)(ws + o);   o += Nn + 16;
    int* cursor = (int*)(ws + o); o += Nn;
    int* bsum = (int*)(ws + o);   o += 128;
    int2* rec = (int2*)(ws + o);  o += (size_t)E * 2;

    hipMemsetAsync(cnt, 0, (size_t)Nn * sizeof(int), stream);

    count_kernel<<<1024, 256, 0, stream>>>(dstp, cnt, E);
    int NB = (Nn + 1023) / 1024;  // 98
    scan_part<<<NB, 1024, 0, stream>>>(cnt, bsum, Nn);
    scan_top<<<1, 128, 0, stream>>>(bsum, NB);
    scan_final<<<NB, 1024, 0, stream>>>(cnt, bsum, offs, cursor, dis, Nn, E);
    fill_kernel<<<1024, 256, 0, stream>>>(srcp, dstp, dis, cursor, rec, E);

    // casts
    cast_bf16_kernel<<<2048, 256, 0, stream>>>((const float4*)emb, (ushort4*)embb, Nn * 128 / 4);
    castT_kernel<<<(128 * 256 + 255) / 256, 256, 0, stream>>>(W1, W1t, 128, 256);
    castT_kernel<<<(256 * 128 + 255) / 256, 256, 0, stream>>>(W2, W2t, 256, 128);

    // layer 1: aggregate emb (bf16 out), GEMM 128->256 + bias + L2 norm (bf16 out)
    agg_kernel<false, true><<<(Nn + 3) / 4, 256, 0, stream>>>(embb, offs, rec, dis, nullptr, axb, Nn);
    mfma_gemm<128, 256, true><<<(Nn + 63) / 64, 256, 0, stream>>>((const ushort*)axb, W1t, b1, (ushort*)xbb, Nn);

    // layer 2: GEMM 256->128 (bf16 out), aggregate + bias (fp32 out)
    mfma_gemm<256, 128, false><<<(Nn + 63) / 64, 256, 0, stream>>>((const ushort*)xbb, W2t, nullptr, (ushort*)h2b, Nn);
    agg_kernel<true, false><<<(Nn + 3) / 4, 256, 0, stream>>>(h2b, offs, rec, dis, b2, d_out, Nn);
}

// Round 4
// 335.197 us; speedup vs baseline: 2.6018x; 1.2741x over previous
//
#include <hip/hip_runtime.h>
#include <hip/hip_bf16.h>

typedef __attribute__((ext_vector_type(8))) short bf16x8;
typedef __attribute__((ext_vector_type(4))) float f32x4;

// ---------------- helpers ----------------

__device__ __forceinline__ ushort f2bf(float f) {
    unsigned int b = __float_as_uint(f);
    unsigned int r = (b + 0x7fffu + ((b >> 16) & 1u)) >> 16;  // RNE
    return (ushort)r;
}
__device__ __forceinline__ float bflo(uint v) { return __uint_as_float(v << 16); }
__device__ __forceinline__ float bfhi(uint v) { return __uint_as_float(v & 0xffff0000u); }

// ---------------- CSR build ----------------

// count in-degree AND record each edge's rank within its dst bucket
__global__ void count_kernel(const int* __restrict__ dst, int* __restrict__ cnt,
                             int* __restrict__ rank, int E) {
    int stride = gridDim.x * blockDim.x;
    for (int e = blockIdx.x * blockDim.x + threadIdx.x; e < E; e += stride)
        rank[e] = atomicAdd(&cnt[dst[e]], 1);
}

__global__ __launch_bounds__(1024) void scan_part(const int* __restrict__ cnt,
                                                  int* __restrict__ bsum, int Nn) {
    int i = blockIdx.x * 1024 + threadIdx.x;
    int v = (i < Nn) ? cnt[i] : 0;
#pragma unroll
    for (int d = 1; d < 64; d <<= 1) v += __shfl_xor(v, d, 64);
    __shared__ int wsums[16];
    if ((threadIdx.x & 63) == 0) wsums[threadIdx.x >> 6] = v;
    __syncthreads();
    if (threadIdx.x == 0) {
        int s = 0;
        for (int w = 0; w < 16; ++w) s += wsums[w];
        bsum[blockIdx.x] = s;
    }
}

// parallel exclusive scan over NB<=128 block sums (1 block, 128 threads)
__global__ __launch_bounds__(128) void scan_top(int* __restrict__ bsum, int NB) {
    int i = threadIdx.x;
    int v = (i < NB) ? bsum[i] : 0;
    int x = v;
#pragma unroll
    for (int d = 1; d < 64; d <<= 1) {
        int y = __shfl_up(x, d, 64);
        if ((i & 63) >= d) x += y;
    }
    __shared__ int w0;
    if (i == 63) w0 = x;
    __syncthreads();
    if (i >= 64) x += w0;
    if (i < NB) bsum[i] = x - v;
}

__global__ __launch_bounds__(1024) void scan_final(const int* __restrict__ cnt,
                                                   const int* __restrict__ bpre,
                                                   int* __restrict__ offs,
                                                   float* __restrict__ dis, int Nn, int E) {
    int i = blockIdx.x * 1024 + threadIdx.x;
    int v = (i < Nn) ? cnt[i] : 0;
    int lane = threadIdx.x & 63, wid = threadIdx.x >> 6;
    int x = v;
#pragma unroll
    for (int d = 1; d < 64; d <<= 1) {
        int y = __shfl_up(x, d, 64);
        if (lane >= d) x += y;
    }
    __shared__ int wsum[16];
    __shared__ int wpre[16];
    if (lane == 63) wsum[wid] = x;
    __syncthreads();
    if (threadIdx.x == 0) {
        int run = 0;
        for (int w = 0; w < 16; ++w) { wpre[w] = run; run += wsum[w]; }
    }
    __syncthreads();
    int excl = x - v + wpre[wid] + bpre[blockIdx.x];
    if (i < Nn) {
        offs[i] = excl;
        dis[i] = rsqrtf((float)v + 1.0f);
    }
    if (blockIdx.x == 0 && threadIdx.x == 0) offs[Nn] = E;
}

// atomic-free bucket fill: position = offs[dst] + rank
__global__ void fill_kernel(const int* __restrict__ src, const int* __restrict__ dst,
                            const int* __restrict__ rank, const int* __restrict__ offs,
                            int* __restrict__ rec, int E) {
    int stride = gridDim.x * blockDim.x;
    for (int e = blockIdx.x * blockDim.x + threadIdx.x; e < E; e += stride)
        rec[offs[dst[e]] + rank[e]] = src[e];
}

// ---------------- casts ----------------

__global__ void cast_bf16_kernel(const float4* __restrict__ in, ushort4* __restrict__ out, int n4) {
    int stride = gridDim.x * blockDim.x;
    for (int i = blockIdx.x * blockDim.x + threadIdx.x; i < n4; i += stride) {
        float4 v = in[i];
        ushort4 o;
        o.x = f2bf(v.x); o.y = f2bf(v.y); o.z = f2bf(v.z); o.w = f2bf(v.w);
        out[i] = o;
    }
}

// Wt[n][k] = bf16(W[k][n]); total = Kd*Nd elements, Wt is [Nd][Kd]
__global__ void castT_kernel(const float* __restrict__ W, ushort* __restrict__ Wt, int Kd, int Nd) {
    int i = blockIdx.x * 256 + threadIdx.x;
    if (i >= Kd * Nd) return;
    int n = i / Kd, k = i % Kd;
    Wt[i] = f2bf(W[(size_t)k * Nd + n]);
}

// ---------------- aggregation over 128 bf16 cols ----------------
// one wave per node; lane owns cols {2*lane, 2*lane+1} packed in one uint.
// 8-wide edge batching (tail-clamped, zero-weighted) for memory-level parallelism.

template <bool BIAS, bool BF16OUT>
__global__ __launch_bounds__(256) void agg_kernel(const uint* __restrict__ tbl,   // [Nn][64]
                                                  const int* __restrict__ offs,
                                                  const int* __restrict__ rec,    // src per edge
                                                  const float* __restrict__ dis,
                                                  const float* __restrict__ bias,
                                                  void* __restrict__ outp, int Nn) {
    int gw = (int)((blockIdx.x * 256 + threadIdx.x) >> 6);
    int lane = threadIdx.x & 63;
    if (gw >= Nn) return;
    float dn = dis[gw];
    int e0 = offs[gw], e1 = offs[gw + 1];
    uint hv = tbl[(size_t)gw * 64 + lane];
    float sw = dn * dn;
    float ax = bflo(hv) * sw, ay = bfhi(hv) * sw;

    for (int base = e0; base < e1; base += 8) {
        int ss[8];
        uint vv[8];
        float ff[8];
#pragma unroll
        for (int j = 0; j < 8; ++j) {
            int e = base + j;
            ss[j] = rec[e < e1 ? e : e1 - 1];
        }
#pragma unroll
        for (int j = 0; j < 8; ++j) vv[j] = tbl[(size_t)ss[j] * 64 + lane];
#pragma unroll
        for (int j = 0; j < 8; ++j) {
            float f = dis[ss[j]] * dn;
            ff[j] = (base + j < e1) ? f : 0.f;
        }
#pragma unroll
        for (int j = 0; j < 8; ++j) {
            ax += bflo(vv[j]) * ff[j];
            ay += bfhi(vv[j]) * ff[j];
        }
    }

    if (BIAS) {
        float2 bv = reinterpret_cast<const float2*>(bias)[lane];
        ax += bv.x; ay += bv.y;
    }
    if (BF16OUT) {
        reinterpret_cast<uint*>(outp)[(size_t)gw * 64 + lane] =
            (uint)f2bf(ax) | ((uint)f2bf(ay) << 16);
    } else {
        float2 o; o.x = ax; o.y = ay;
        reinterpret_cast<float2*>(outp)[(size_t)gw * 64 + lane] = o;
    }
}

// ---------------- MFMA GEMM: C[M,N] = A[M,K] @ W[K,N], A bf16 row-major, Wt[n][k] bf16 ----------------
// block = 4 waves, tile 64 rows x N cols; wave w owns cols [w*N/4, (w+1)*N/4).
// mfma_f32_16x16x32_bf16: C/D col=lane&15, row=(lane>>4)*4+reg  [measured m89].
// FIN: add bias, L2-normalize rows (cross-wave via LDS), write bf16. else: plain bf16 write.

template <int K, int N, bool FIN>
__global__ __launch_bounds__(256) void mfma_gemm(const ushort* __restrict__ A,
                                                 const ushort* __restrict__ Wt,
                                                 const float* __restrict__ bias,
                                                 ushort* __restrict__ Cb, int M) {
    constexpr int NS = N / 64;   // n-subtiles per wave
    constexpr int KS = K / 32;   // k-steps
    int lane = threadIdx.x & 63, wid = threadIdx.x >> 6;
    int m0 = blockIdx.x * 64;
    int koff = (lane >> 4) * 8;

    const bf16x8* ap[4];
#pragma unroll
    for (int ms = 0; ms < 4; ++ms) {
        int r = m0 + ms * 16 + (lane & 15);
        if (r >= M) r = M - 1;
        ap[ms] = reinterpret_cast<const bf16x8*>(A + (size_t)r * K + koff);
    }
    const bf16x8* bp[NS];
#pragma unroll
    for (int ns = 0; ns < NS; ++ns) {
        int c = wid * (N / 4) + ns * 16 + (lane & 15);
        bp[ns] = reinterpret_cast<const bf16x8*>(Wt + (size_t)c * K + koff);
    }

    f32x4 acc[4][NS];
#pragma unroll
    for (int ms = 0; ms < 4; ++ms)
#pragma unroll
        for (int ns = 0; ns < NS; ++ns) acc[ms][ns] = (f32x4){0.f, 0.f, 0.f, 0.f};

#pragma unroll
    for (int ks = 0; ks < KS; ++ks) {
        bf16x8 a[4], b[NS];
#pragma unroll
        for (int ms = 0; ms < 4; ++ms) a[ms] = ap[ms][ks * 4];
#pragma unroll
        for (int ns = 0; ns < NS; ++ns) b[ns] = bp[ns][ks * 4];
#pragma unroll
        for (int ms = 0; ms < 4; ++ms)
#pragma unroll
            for (int ns = 0; ns < NS; ++ns)
                acc[ms][ns] = __builtin_amdgcn_mfma_f32_16x16x32_bf16(a[ms], b[ns], acc[ms][ns], 0, 0, 0);
    }

    if (FIN) {
        float bv[NS];
#pragma unroll
        for (int ns = 0; ns < NS; ++ns) bv[ns] = bias[wid * (N / 4) + ns * 16 + (lane & 15)];
        float ps[4][4];
#pragma unroll
        for (int ms = 0; ms < 4; ++ms)
#pragma unroll
            for (int r = 0; r < 4; ++r) {
                float s = 0.f;
#pragma unroll
                for (int ns = 0; ns < NS; ++ns) {
                    float v = acc[ms][ns][r] + bv[ns];
                    acc[ms][ns][r] = v;
                    s += v * v;
                }
                ps[ms][r] = s;
            }
#pragma unroll
        for (int d = 1; d < 16; d <<= 1)
#pragma unroll
            for (int ms = 0; ms < 4; ++ms)
#pragma unroll
                for (int r = 0; r < 4; ++r) ps[ms][r] += __shfl_xor(ps[ms][r], d, 64);
        __shared__ float ssl[4][64];
        if ((lane & 15) == 0) {
#pragma unroll
            for (int ms = 0; ms < 4; ++ms)
#pragma unroll
                for (int r = 0; r < 4; ++r) ssl[wid][ms * 16 + (lane >> 4) * 4 + r] = ps[ms][r];
        }
        __syncthreads();
#pragma unroll
        for (int ms = 0; ms < 4; ++ms)
#pragma unroll
            for (int r = 0; r < 4; ++r) {
                int rt = ms * 16 + (lane >> 4) * 4 + r;
                float tot = ssl[0][rt] + ssl[1][rt] + ssl[2][rt] + ssl[3][rt];
                float inv = 1.0f / fmaxf(sqrtf(tot), 1e-12f);
                int row = m0 + rt;
                if (row < M) {
#pragma unroll
                    for (int ns = 0; ns < NS; ++ns)
                        Cb[(size_t)row * N + wid * (N / 4) + ns * 16 + (lane & 15)] =
                            f2bf(acc[ms][ns][r] * inv);
                }
            }
    } else {
#pragma unroll
        for (int ms = 0; ms < 4; ++ms)
#pragma unroll
            for (int r = 0; r < 4; ++r) {
                int row = m0 + ms * 16 + (lane >> 4) * 4 + r;
                if (row < M) {
#pragma unroll
                    for (int ns = 0; ns < NS; ++ns)
                        Cb[(size_t)row * N + wid * (N / 4) + ns * 16 + (lane & 15)] =
                            f2bf(acc[ms][ns][r]);
                }
            }
    }
}

// ---------------- launch ----------------

extern "C" void kernel_launch(void* const* d_in, const int* in_sizes, int n_in,
                              void* d_out, int out_size, void* d_ws, size_t ws_size,
                              hipStream_t stream) {
    const float* emb = (const float*)d_in[0];
    const float* W1 = (const float*)d_in[1];
    const float* b1 = (const float*)d_in[2];
    const float* W2 = (const float*)d_in[3];
    const float* b2 = (const float*)d_in[4];
    const int* eidx = (const int*)d_in[5];

    const int Nn = in_sizes[0] / 128;   // 100000
    const int E = in_sizes[5] / 2;      // 1600000
    const int* srcp = eidx;
    const int* dstp = eidx + E;

    float* ws = (float*)d_ws;
    size_t o = 0;
    uint* embb = (uint*)(ws + o);  o += (size_t)Nn * 64;   // emb bf16 [Nn][128]
    uint* axb = (uint*)(ws + o);   o += (size_t)Nn * 64;   // agg1 out bf16 [Nn][128]
    uint* xbb = (uint*)(ws + o);   o += (size_t)Nn * 128;  // layer1 out bf16 [Nn][256]
    uint* h2b = (uint*)(ws + o);   o += (size_t)Nn * 64;   // layer2 gemm out bf16 [Nn][128]
    ushort* W1t = (ushort*)(ws + o); o += 128 * 256 / 2;   // [256][128]
    ushort* W2t = (ushort*)(ws + o); o += 256 * 128 / 2;   // [128][256]
    float* dis = ws + o;    o += Nn;
    int* cnt = (int*)(ws + o);    o += Nn;
    int* offs = (int*)(ws + o);   o += Nn + 16;
    int* bsum = (int*)(ws + o);   o += 128;
    int* rank = (int*)(ws + o);   o += E;
    int* rec = (int*)(ws + o);    o += E;

    hipMemsetAsync(cnt, 0, (size_t)Nn * sizeof(int), stream);

    count_kernel<<<1024, 256, 0, stream>>>(dstp, cnt, rank, E);
    int NB = (Nn + 1023) / 1024;  // 98
    scan_part<<<NB, 1024, 0, stream>>>(cnt, bsum, Nn);
    scan_top<<<1, 128, 0, stream>>>(bsum, NB);
    scan_final<<<NB, 1024, 0, stream>>>(cnt, bsum, offs, dis, Nn, E);
    fill_kernel<<<1024, 256, 0, stream>>>(srcp, dstp, rank, offs, rec, E);

    // casts
    cast_bf16_kernel<<<2048, 256, 0, stream>>>((const float4*)emb, (ushort4*)embb, Nn * 128 / 4);
    castT_kernel<<<(128 * 256 + 255) / 256, 256, 0, stream>>>(W1, W1t, 128, 256);
    castT_kernel<<<(256 * 128 + 255) / 256, 256, 0, stream>>>(W2, W2t, 256, 128);

    // layer 1: aggregate emb (bf16 out), GEMM 128->256 + bias + L2 norm (bf16 out)
    agg_kernel<false, true><<<(Nn + 3) / 4, 256, 0, stream>>>(embb, offs, rec, dis, nullptr, axb, Nn);
    mfma_gemm<128, 256, true><<<(Nn + 63) / 64, 256, 0, stream>>>((const ushort*)axb, W1t, b1, (ushort*)xbb, Nn);

    // layer 2: GEMM 256->128 (bf16 out), aggregate + bias (fp32 out)
    mfma_gemm<256, 128, false><<<(Nn + 63) / 64, 256, 0, stream>>>((const ushort*)xbb, W2t, nullptr, (ushort*)h2b, Nn);
    agg_kernel<true, false><<<(Nn + 3) / 4, 256, 0, stream>>>(h2b, offs, rec, dis, b2, d_out, Nn);
}